// Round 7
// baseline (717.638 us; speedup 1.0000x reference)
//
#include <hip/hip_runtime.h>

#define N_NODES 50000
#define N_EDGES 600000
#define XS_STRIDE 132            // LDS row stride: 128 + 4 pad
#define PANEL ((size_t)N_NODES * 16)   // floats per 16-col feature panel

// ---------------- graph build (degree-sorted permuted node space) ----------------

__global__ void count_edges(const int* __restrict__ dst, int* __restrict__ cnt) {
    int e = blockIdx.x * blockDim.x + threadIdx.x;
    if (e < N_EDGES) atomicAdd(&cnt[dst[e]], 1);
}

__global__ void bucket_count(const int* __restrict__ cnt, int* __restrict__ bcnt) {
    int i = blockIdx.x * blockDim.x + threadIdx.x;
    if (i < N_NODES) atomicAdd(&bcnt[min(cnt[i], 63)], 1);
}

__global__ void bucket_scan(const int* __restrict__ bcnt, int* __restrict__ bstart) {
    if (threadIdx.x == 0) {
        int running = 0;
        for (int i = 0; i < 64; ++i) { bstart[i] = running; running += bcnt[i]; }
    }
}

// Counting-sort nodes by degree; also reserve CSR ranges and compute dinv.
// Permuted index p: all intermediate tensors (panels, CSR) live in p-space.
__global__ void build_perm(const int* __restrict__ cnt, const int* __restrict__ bstart,
                           int* __restrict__ bfill, int* __restrict__ perm,
                           int* __restrict__ inv, int* __restrict__ cnt_p,
                           float* __restrict__ dinv_p, int* __restrict__ start_p,
                           int* __restrict__ total) {
    int v = blockIdx.x * blockDim.x + threadIdx.x;
    if (v < N_NODES) {
        int c = cnt[v];
        int d = min(c, 63);
        int pos = bstart[d] + atomicAdd(&bfill[d], 1);
        perm[pos] = v;
        inv[v] = pos;
        cnt_p[pos] = c;
        dinv_p[pos] = 1.0f / sqrtf((float)(c + 1));   // +1 self-loop
        start_p[pos] = atomicAdd(total, c);
    }
}

// edge[pos] = {src_permuted, bits(dinv[src])} -> single 8B load in the gather loop
__global__ void csr_fill(const int* __restrict__ srcArr, const int* __restrict__ dstArr,
                         const int* __restrict__ inv, const int* __restrict__ start_p,
                         int* __restrict__ fill_p, const float* __restrict__ dinv_p,
                         int2* __restrict__ edge) {
    int e = blockIdx.x * blockDim.x + threadIdx.x;
    if (e < N_EDGES) {
        int dp = inv[dstArr[e]];
        int sp = inv[srcArr[e]];
        int pos = start_p[dp] + atomicAdd(&fill_p[dp], 1);
        edge[pos] = make_int2(sp, __float_as_int(dinv_p[sp]));
    }
}

// ---------------- dense GEMM [N,128]@[128,128] -> panel output ----------------
// block = 256 threads, tile = 32 rows x 128 cols, micro-tile 2x8.
// Grid 1563 blocks -> ~8 blocks/CU (LDS 16.9KB), high occupancy.
// MODE 0: input row-major x, rows gathered via perm. MODE 1: input panel layout (p-space).

template <int MODE>
__global__ __launch_bounds__(256) void gemm128_t(const float* __restrict__ X,
                                                 const float* __restrict__ W,
                                                 const int* __restrict__ perm,
                                                 float* __restrict__ T) {
    __shared__ float xs[32 * XS_STRIDE];
    int tid = threadIdx.x;
    int row0 = blockIdx.x * 32;

    // stage 32x128 floats = 1024 float4, 4 per thread
    #pragma unroll
    for (int i = 0; i < 4; ++i) {
        int fi = tid + i * 256;
        int r  = fi >> 5;              // 32 float4 per row
        int c4 = (fi & 31) << 2;
        float4 v = make_float4(0.f, 0.f, 0.f, 0.f);
        int rg = row0 + r;
        if (rg < N_NODES) {
            if (MODE == 0) {
                int tv = perm[rg];     // p-space row rg holds true node perm[rg]
                v = *(const float4*)&X[(size_t)tv * 128 + c4];
            } else {
                int f = c4 >> 4, off = c4 & 15;
                v = *(const float4*)&X[(size_t)f * PANEL + (size_t)rg * 16 + off];
            }
        }
        float* p = &xs[r * XS_STRIDE + c4];
        p[0] = v.x; p[1] = v.y; p[2] = v.z; p[3] = v.w;
    }
    __syncthreads();

    int cg = tid & 15, rg = tid >> 4;
    int c0 = cg * 8, r0 = rg * 2;
    float acc[2][8];
    #pragma unroll
    for (int i = 0; i < 2; ++i)
        #pragma unroll
        for (int j = 0; j < 8; ++j) acc[i][j] = 0.f;

    for (int k0 = 0; k0 < 128; k0 += 4) {
        float4 a[2];
        #pragma unroll
        for (int i = 0; i < 2; ++i) a[i] = *(const float4*)&xs[(r0 + i) * XS_STRIDE + k0];
        #pragma unroll
        for (int kk = 0; kk < 4; ++kk) {
            float4 blo = *(const float4*)&W[(k0 + kk) * 128 + c0];
            float4 bhi = *(const float4*)&W[(k0 + kk) * 128 + c0 + 4];
            #pragma unroll
            for (int i = 0; i < 2; ++i) {
                float av = (kk == 0) ? a[i].x : (kk == 1) ? a[i].y : (kk == 2) ? a[i].z : a[i].w;
                acc[i][0] = fmaf(av, blo.x, acc[i][0]);
                acc[i][1] = fmaf(av, blo.y, acc[i][1]);
                acc[i][2] = fmaf(av, blo.z, acc[i][2]);
                acc[i][3] = fmaf(av, blo.w, acc[i][3]);
                acc[i][4] = fmaf(av, bhi.x, acc[i][4]);
                acc[i][5] = fmaf(av, bhi.y, acc[i][5]);
                acc[i][6] = fmaf(av, bhi.z, acc[i][6]);
                acc[i][7] = fmaf(av, bhi.w, acc[i][7]);
            }
        }
    }

    int f = c0 >> 4, off = c0 & 15;
    #pragma unroll
    for (int i = 0; i < 2; ++i) {
        int r = row0 + r0 + i;
        if (r < N_NODES) {
            float* base = &T[(size_t)f * PANEL + (size_t)r * 16 + off];
            *(float4*)&base[0] = make_float4(acc[i][0], acc[i][1], acc[i][2], acc[i][3]);
            *(float4*)&base[4] = make_float4(acc[i][4], acc[i][5], acc[i][6], acc[i][7]);
        }
    }
}

// ---------------- aggregation over panels (p-space, degree-sorted) ----------------
// blockIdx % 8 = feature panel f (-> XCD f round-robin; 3.2MB panel ~ L2-resident).
// block = 256 = 64 nodes x 4 lanes (float4). Degree sorting makes the 16 nodes in
// each wave near-uniform degree -> minimal exec-mask waste in the edge loop.

__global__ __launch_bounds__(256) void gcn_aggregate_pn(
        const float* __restrict__ T, const int* __restrict__ start,
        const int* __restrict__ cnt, const int2* __restrict__ edge,
        const float* __restrict__ dinv, const float* __restrict__ bias,
        float* __restrict__ outp) {
    int f  = blockIdx.x & 7;
    int nb = blockIdx.x >> 3;
    int tid = threadIdx.x;
    int v = nb * 64 + (tid >> 2);
    if (v >= N_NODES) return;
    int j4 = (tid & 3) << 2;

    const float* __restrict__ Tp = T + (size_t)f * PANEL;
    float dv = dinv[v];
    const float4 tv = *(const float4*)&Tp[(size_t)v * 16 + j4];
    float4 acc = make_float4(dv * tv.x, dv * tv.y, dv * tv.z, dv * tv.w);

    int beg = start[v], end = beg + cnt[v];
    int e = beg;
    for (; e + 4 <= end; e += 4) {
        int2 e0 = edge[e],     e1 = edge[e + 1];
        int2 e2 = edge[e + 2], e3 = edge[e + 3];
        float w0 = __int_as_float(e0.y), w1 = __int_as_float(e1.y);
        float w2 = __int_as_float(e2.y), w3 = __int_as_float(e3.y);
        const float4 t0 = *(const float4*)&Tp[(size_t)e0.x * 16 + j4];
        const float4 t1 = *(const float4*)&Tp[(size_t)e1.x * 16 + j4];
        const float4 t2 = *(const float4*)&Tp[(size_t)e2.x * 16 + j4];
        const float4 t3 = *(const float4*)&Tp[(size_t)e3.x * 16 + j4];
        acc.x = fmaf(w0, t0.x, fmaf(w1, t1.x, fmaf(w2, t2.x, fmaf(w3, t3.x, acc.x))));
        acc.y = fmaf(w0, t0.y, fmaf(w1, t1.y, fmaf(w2, t2.y, fmaf(w3, t3.y, acc.y))));
        acc.z = fmaf(w0, t0.z, fmaf(w1, t1.z, fmaf(w2, t2.z, fmaf(w3, t3.z, acc.z))));
        acc.w = fmaf(w0, t0.w, fmaf(w1, t1.w, fmaf(w2, t2.w, fmaf(w3, t3.w, acc.w))));
    }
    for (; e < end; ++e) {
        int2 e0 = edge[e];
        float w0 = __int_as_float(e0.y);
        const float4 t0 = *(const float4*)&Tp[(size_t)e0.x * 16 + j4];
        acc.x = fmaf(w0, t0.x, acc.x);
        acc.y = fmaf(w0, t0.y, acc.y);
        acc.z = fmaf(w0, t0.z, acc.z);
        acc.w = fmaf(w0, t0.w, acc.w);
    }

    const float4 b4 = *(const float4*)&bias[f * 16 + j4];
    float4 r;
    r.x = fmaxf(fmaf(dv, acc.x, b4.x), 0.f);
    r.y = fmaxf(fmaf(dv, acc.y, b4.y), 0.f);
    r.z = fmaxf(fmaf(dv, acc.z, b4.z), 0.f);
    r.w = fmaxf(fmaf(dv, acc.w, b4.w), 0.f);
    *(float4*)&outp[(size_t)f * PANEL + (size_t)v * 16 + j4] = r;
}

// ---------------- final linear [N,128]@[128,32] + bias (p-space in, true-order out) ----

__global__ __launch_bounds__(256) void gemm_final_pn(
        const float* __restrict__ Hp, const float* __restrict__ Wl,
        const float* __restrict__ bl, const int* __restrict__ perm,
        float* __restrict__ out32) {
    __shared__ float sh[8 * 128];
    int tid = threadIdx.x;
    int g = tid >> 5, lane = tid & 31;
    int v = blockIdx.x * 8 + g;          // grid = 6250 exactly
    int c4 = lane << 2;
    int f = c4 >> 4, off = c4 & 15;
    const float4 hv = *(const float4*)&Hp[(size_t)f * PANEL + (size_t)v * 16 + off];
    *(float4*)&sh[g * 128 + c4] = hv;
    __syncthreads();

    float o = bl[lane];
    const float* hrow = &sh[g * 128];
    #pragma unroll 8
    for (int j = 0; j < 128; ++j)
        o = fmaf(hrow[j], Wl[j * 32 + lane], o);
    int t = perm[v];
    out32[(size_t)t * 32 + lane] = o;
}

// ---------------- launch ----------------

extern "C" void kernel_launch(void* const* d_in, const int* in_sizes, int n_in,
                              void* d_out, int out_size, void* d_ws, size_t ws_size,
                              hipStream_t stream) {
    const float* x      = (const float*)d_in[0];
    const int*   ei     = (const int*)d_in[1];
    const int*   srcArr = ei;
    const int*   dstArr = ei + N_EDGES;
    const float* W1 = (const float*)d_in[2];
    const float* b1 = (const float*)d_in[3];
    const float* W2 = (const float*)d_in[4];
    const float* b2 = (const float*)d_in[5];
    const float* W3 = (const float*)d_in[6];
    const float* b3 = (const float*)d_in[7];
    const float* Wl = (const float*)d_in[8];
    const float* bl = (const float*)d_in[9];
    float* out = (float*)d_out;

    // workspace layout (~57.5 MB)
    float* bufA   = (float*)d_ws;                       // N*128 (8 panels)
    float* bufB   = bufA + (size_t)N_NODES * 128;       // N*128 (8 panels)
    int2*  edge   = (int2*)(bufB + (size_t)N_NODES * 128); // E
    float* dinv_p = (float*)(edge + N_EDGES);           // N
    int*   cnt    = (int*)(dinv_p + N_NODES);           // N   <- zero from here
    int*   fill_p = cnt + N_NODES;                      // N
    int*   total  = fill_p + N_NODES;                   // 1
    int*   bcnt   = total + 1;                          // 64
    int*   bfill  = bcnt + 64;                          // 64  <- zero to here
    int*   bstart = bfill + 64;                         // 64
    int*   perm   = bstart + 64;                        // N
    int*   inv    = perm + N_NODES;                     // N
    int*   cnt_p  = inv + N_NODES;                      // N
    int*   start_p= cnt_p + N_NODES;                    // N

    hipMemsetAsync(cnt, 0, (size_t)(2 * N_NODES + 129) * sizeof(int), stream);
    count_edges <<<(N_EDGES + 255) / 256, 256, 0, stream>>>(dstArr, cnt);
    bucket_count<<<(N_NODES + 255) / 256, 256, 0, stream>>>(cnt, bcnt);
    bucket_scan <<<1, 64, 0, stream>>>(bcnt, bstart);
    build_perm  <<<(N_NODES + 255) / 256, 256, 0, stream>>>(cnt, bstart, bfill, perm, inv,
                                                            cnt_p, dinv_p, start_p, total);
    csr_fill    <<<(N_EDGES + 255) / 256, 256, 0, stream>>>(srcArr, dstArr, inv, start_p,
                                                            fill_p, dinv_p, edge);

    const int GEMM_GRID = (N_NODES + 31) / 32;           // 1563
    const int AGG_GRID  = ((N_NODES + 63) / 64) * 8;     // 6256: blockIdx%8 = panel/XCD

    gemm128_t<0><<<GEMM_GRID, 256, 0, stream>>>(x, W1, perm, bufA);
    gcn_aggregate_pn<<<AGG_GRID, 256, 0, stream>>>(bufA, start_p, cnt_p, edge, dinv_p, b1, bufB);
    gemm128_t<1><<<GEMM_GRID, 256, 0, stream>>>(bufB, W2, perm, bufA);
    gcn_aggregate_pn<<<AGG_GRID, 256, 0, stream>>>(bufA, start_p, cnt_p, edge, dinv_p, b2, bufB);
    gemm128_t<1><<<GEMM_GRID, 256, 0, stream>>>(bufB, W3, perm, bufA);
    gcn_aggregate_pn<<<AGG_GRID, 256, 0, stream>>>(bufA, start_p, cnt_p, edge, dinv_p, b3, bufB);
    gemm_final_pn<<<N_NODES / 8, 256, 0, stream>>>(bufB, Wl, bl, perm, out);
}

// Round 10
// 494.411 us; speedup vs baseline: 1.4515x; 1.4515x over previous
//
#include <hip/hip_runtime.h>

#define N_NODES 50000
#define NP      50016                      // panel rows incl. sentinel row 50000
#define N_EDGES 600000
#define EDGE_CAP 800000                    // padded edge capacity (<= E + 3N)
#define SENT    50000                      // sentinel src: T row kept zero
#define XS_STRIDE 132                      // LDS row stride: 128 + 4 pad
#define PANEL ((size_t)NP * 16)            // floats per 16-col feature panel

// ---------------- graph build ----------------

__global__ void count_edges(const int* __restrict__ dst, int* __restrict__ cnt) {
    int e = blockIdx.x * blockDim.x + threadIdx.x;
    if (e < N_EDGES) atomicAdd(&cnt[dst[e]], 1);
}

// start[v] = atomicAdd(total, padded_c)  (uniform-address atomic -> wave-coalesced).
// Nondeterministic row PLACEMENT is fine: per-row content is canonicalized by
// sort_rows below, so no float math depends on placement/fill order.
__global__ void reserve_rows(const int* __restrict__ cnt, int* __restrict__ start,
                             int* __restrict__ cnt_pad, int* __restrict__ total,
                             float* __restrict__ dinv, unsigned short* __restrict__ col16) {
    int i = blockIdx.x * blockDim.x + threadIdx.x;
    if (i < N_NODES) {
        int c = cnt[i];
        int pc = (c + 3) & ~3;
        int s = atomicAdd(total, pc);
        start[i] = s;
        cnt_pad[i] = pc;
        dinv[i] = 1.0f / sqrtf((float)(c + 1));   // +1 self-loop
        for (int p = s + c; p < s + pc; ++p) col16[p] = (unsigned short)SENT;
    }
}

__global__ void csr_fill(const int* __restrict__ srcArr, const int* __restrict__ dstArr,
                         const int* __restrict__ start, int* __restrict__ fill,
                         unsigned short* __restrict__ col16) {
    int e = blockIdx.x * blockDim.x + threadIdx.x;
    if (e < N_EDGES) {
        int d = dstArr[e];
        int pos = start[d] + atomicAdd(&fill[d], 1);
        col16[pos] = (unsigned short)srcArr[e];
    }
}

// DETERMINISM: canonical per-row order (ascending src) so every replay sums each
// row identically -> bitwise-stable output (bf16-boundary ulp flips killed r9).
// Sentinels (SENT = max) already sit at the end; sort only the c real entries.
__global__ void sort_rows(const int* __restrict__ start, const int* __restrict__ cnt,
                          unsigned short* __restrict__ col16) {
    int v = blockIdx.x * blockDim.x + threadIdx.x;
    if (v >= N_NODES) return;
    int beg = start[v], c = cnt[v];
    for (int i = 1; i < c; ++i) {
        unsigned short key = col16[beg + i];
        int j = i - 1;
        while (j >= 0 && col16[beg + j] > key) {
            col16[beg + j + 1] = col16[beg + j];
            --j;
        }
        col16[beg + j + 1] = key;
    }
}

// Zero the sentinel rows (row 50000 of each panel, both buffers) and dinv[SENT].
__global__ void zero_pad(float* __restrict__ bufA, float* __restrict__ bufB,
                         float* __restrict__ dinv) {
    int i = threadIdx.x;                 // 256 threads: 2 bufs x 8 panels x 16
    float* buf = (i & 128) ? bufB : bufA;
    int f = (i >> 4) & 7, j = i & 15;
    buf[(size_t)f * PANEL + (size_t)SENT * 16 + j] = 0.f;
    if (i == 0) dinv[SENT] = 0.f;
}

// ---------------- dense GEMM [N,128]@[128,128] -> panel output ----------------
// block = 256 threads, tile = 32 rows x 128 cols, micro-tile 2x8.
// MODE 0: input row-major x. MODE 1: input panel layout.

template <int MODE>
__global__ __launch_bounds__(256) void gemm128_t(const float* __restrict__ X,
                                                 const float* __restrict__ W,
                                                 float* __restrict__ T) {
    __shared__ float xs[32 * XS_STRIDE];
    int tid = threadIdx.x;
    int row0 = blockIdx.x * 32;

    #pragma unroll
    for (int i = 0; i < 4; ++i) {
        int fi = tid + i * 256;
        int r  = fi >> 5;
        int c4 = (fi & 31) << 2;
        float4 v = make_float4(0.f, 0.f, 0.f, 0.f);
        int rg = row0 + r;
        if (rg < N_NODES) {
            if (MODE == 0) {
                v = *(const float4*)&X[(size_t)rg * 128 + c4];
            } else {
                int f = c4 >> 4, off = c4 & 15;
                v = *(const float4*)&X[(size_t)f * PANEL + (size_t)rg * 16 + off];
            }
        }
        float* p = &xs[r * XS_STRIDE + c4];
        p[0] = v.x; p[1] = v.y; p[2] = v.z; p[3] = v.w;
    }
    __syncthreads();

    int cg = tid & 15, rg = tid >> 4;
    int c0 = cg * 8, r0 = rg * 2;
    float acc[2][8];
    #pragma unroll
    for (int i = 0; i < 2; ++i)
        #pragma unroll
        for (int j = 0; j < 8; ++j) acc[i][j] = 0.f;

    for (int k0 = 0; k0 < 128; k0 += 4) {
        float4 a[2];
        #pragma unroll
        for (int i = 0; i < 2; ++i) a[i] = *(const float4*)&xs[(r0 + i) * XS_STRIDE + k0];
        #pragma unroll
        for (int kk = 0; kk < 4; ++kk) {
            float4 blo = *(const float4*)&W[(k0 + kk) * 128 + c0];
            float4 bhi = *(const float4*)&W[(k0 + kk) * 128 + c0 + 4];
            #pragma unroll
            for (int i = 0; i < 2; ++i) {
                float av = (kk == 0) ? a[i].x : (kk == 1) ? a[i].y : (kk == 2) ? a[i].z : a[i].w;
                acc[i][0] = fmaf(av, blo.x, acc[i][0]);
                acc[i][1] = fmaf(av, blo.y, acc[i][1]);
                acc[i][2] = fmaf(av, blo.z, acc[i][2]);
                acc[i][3] = fmaf(av, blo.w, acc[i][3]);
                acc[i][4] = fmaf(av, bhi.x, acc[i][4]);
                acc[i][5] = fmaf(av, bhi.y, acc[i][5]);
                acc[i][6] = fmaf(av, bhi.z, acc[i][6]);
                acc[i][7] = fmaf(av, bhi.w, acc[i][7]);
            }
        }
    }

    int f = c0 >> 4, off = c0 & 15;
    #pragma unroll
    for (int i = 0; i < 2; ++i) {
        int r = row0 + r0 + i;
        if (r < N_NODES) {
            float* base = &T[(size_t)f * PANEL + (size_t)r * 16 + off];
            *(float4*)&base[0] = make_float4(acc[i][0], acc[i][1], acc[i][2], acc[i][3]);
            *(float4*)&base[4] = make_float4(acc[i][4], acc[i][5], acc[i][6], acc[i][7]);
        }
    }
}

// ---------------- aggregation over panels ----------------
// blockIdx % 8 = feature panel f (-> XCD f round-robin; 3.2MB panel ~L2-resident).
// block = 256 = 64 nodes x 4 lanes (float4 per lane). u16 srcs, padded to x4
// with sentinel; dinv[src] from 200KB L2-hot table. Sequential edge order ->
// deterministic sum (rows pre-sorted).

__global__ __launch_bounds__(256) void gcn_aggregate_pn(
        const float* __restrict__ T, const int* __restrict__ start,
        const int* __restrict__ cnt_pad, const unsigned short* __restrict__ col16,
        const float* __restrict__ dinv, const float* __restrict__ bias,
        float* __restrict__ outp) {
    int f  = blockIdx.x & 7;
    int nb = blockIdx.x >> 3;
    int tid = threadIdx.x;
    int v = nb * 64 + (tid >> 2);
    if (v >= N_NODES) return;
    int j4 = (tid & 3) << 2;

    const float* __restrict__ Tp = T + (size_t)f * PANEL;
    float dv = dinv[v];
    const float4 tv = *(const float4*)&Tp[(size_t)v * 16 + j4];
    float4 acc = make_float4(dv * tv.x, dv * tv.y, dv * tv.z, dv * tv.w);

    int beg = start[v], end = beg + cnt_pad[v];      // multiple of 4, aligned
    for (int e = beg; e < end; e += 4) {
        ushort4 c4v = *(const ushort4*)&col16[e];
        int s0 = c4v.x, s1 = c4v.y, s2 = c4v.z, s3 = c4v.w;
        float w0 = dinv[s0], w1 = dinv[s1], w2 = dinv[s2], w3 = dinv[s3];
        const float4 t0 = *(const float4*)&Tp[(size_t)s0 * 16 + j4];
        const float4 t1 = *(const float4*)&Tp[(size_t)s1 * 16 + j4];
        const float4 t2 = *(const float4*)&Tp[(size_t)s2 * 16 + j4];
        const float4 t3 = *(const float4*)&Tp[(size_t)s3 * 16 + j4];
        acc.x = fmaf(w0, t0.x, fmaf(w1, t1.x, fmaf(w2, t2.x, fmaf(w3, t3.x, acc.x))));
        acc.y = fmaf(w0, t0.y, fmaf(w1, t1.y, fmaf(w2, t2.y, fmaf(w3, t3.y, acc.y))));
        acc.z = fmaf(w0, t0.z, fmaf(w1, t1.z, fmaf(w2, t2.z, fmaf(w3, t3.z, acc.z))));
        acc.w = fmaf(w0, t0.w, fmaf(w1, t1.w, fmaf(w2, t2.w, fmaf(w3, t3.w, acc.w))));
    }

    const float4 b4 = *(const float4*)&bias[f * 16 + j4];
    float4 r;
    r.x = fmaxf(fmaf(dv, acc.x, b4.x), 0.f);
    r.y = fmaxf(fmaf(dv, acc.y, b4.y), 0.f);
    r.z = fmaxf(fmaf(dv, acc.z, b4.z), 0.f);
    r.w = fmaxf(fmaf(dv, acc.w, b4.w), 0.f);
    *(float4*)&outp[(size_t)f * PANEL + (size_t)v * 16 + j4] = r;
}

// ---------------- final linear [N,128]@[128,32] + bias, panel input ----------------

__global__ __launch_bounds__(256) void gemm_final_pn(
        const float* __restrict__ Hp, const float* __restrict__ Wl,
        const float* __restrict__ bl, float* __restrict__ out32) {
    __shared__ float sh[8 * 128];
    int tid = threadIdx.x;
    int g = tid >> 5, lane = tid & 31;
    int v = blockIdx.x * 8 + g;          // grid = 6250 exactly
    int c4 = lane << 2;
    int f = c4 >> 4, off = c4 & 15;
    const float4 hv = *(const float4*)&Hp[(size_t)f * PANEL + (size_t)v * 16 + off];
    *(float4*)&sh[g * 128 + c4] = hv;
    __syncthreads();

    float o = bl[lane];
    const float* hrow = &sh[g * 128];
    #pragma unroll 8
    for (int j = 0; j < 128; ++j)
        o = fmaf(hrow[j], Wl[j * 32 + lane], o);
    out32[(size_t)v * 32 + lane] = o;
}

// ---------------- launch ----------------

extern "C" void kernel_launch(void* const* d_in, const int* in_sizes, int n_in,
                              void* d_out, int out_size, void* d_ws, size_t ws_size,
                              hipStream_t stream) {
    const float* x      = (const float*)d_in[0];
    const int*   ei     = (const int*)d_in[1];
    const int*   srcArr = ei;
    const int*   dstArr = ei + N_EDGES;
    const float* W1 = (const float*)d_in[2];
    const float* b1 = (const float*)d_in[3];
    const float* W2 = (const float*)d_in[4];
    const float* b2 = (const float*)d_in[5];
    const float* W3 = (const float*)d_in[6];
    const float* b3 = (const float*)d_in[7];
    const float* Wl = (const float*)d_in[8];
    const float* bl = (const float*)d_in[9];
    float* out = (float*)d_out;

    // workspace layout (~54 MB)
    float* bufA   = (float*)d_ws;                             // 8*PANEL
    float* bufB   = bufA + 8 * PANEL;                         // 8*PANEL
    unsigned short* col16 = (unsigned short*)(bufB + 8 * PANEL); // EDGE_CAP u16
    float* dinv   = (float*)(col16 + EDGE_CAP);               // N+1
    int*   cnt    = (int*)(dinv + N_NODES + 1);               // N   <- memset base
    int*   fill   = cnt + N_NODES;                            // N
    int*   total  = fill + N_NODES;                           // 1   <- memset end
    int*   start  = total + 1;                                // N
    int*   cnt_pad= start + N_NODES;                          // N

    hipMemsetAsync(cnt, 0, (size_t)(2 * N_NODES + 1) * sizeof(int), stream);
    count_edges <<<(N_EDGES + 255) / 256, 256, 0, stream>>>(dstArr, cnt);
    reserve_rows<<<(N_NODES + 255) / 256, 256, 0, stream>>>(cnt, start, cnt_pad, total, dinv, col16);
    csr_fill    <<<(N_EDGES + 255) / 256, 256, 0, stream>>>(srcArr, dstArr, start, fill, col16);
    sort_rows   <<<(N_NODES + 255) / 256, 256, 0, stream>>>(start, cnt, col16);
    zero_pad    <<<1, 256, 0, stream>>>(bufA, bufB, dinv);

    const int GEMM_GRID = (N_NODES + 31) / 32;           // 1563
    const int AGG_GRID  = ((N_NODES + 63) / 64) * 8;     // 6256: blockIdx%8 = panel/XCD

    gemm128_t<0><<<GEMM_GRID, 256, 0, stream>>>(x, W1, bufA);
    gcn_aggregate_pn<<<AGG_GRID, 256, 0, stream>>>(bufA, start, cnt_pad, col16, dinv, b1, bufB);
    gemm128_t<1><<<GEMM_GRID, 256, 0, stream>>>(bufB, W2, bufA);
    gcn_aggregate_pn<<<AGG_GRID, 256, 0, stream>>>(bufA, start, cnt_pad, col16, dinv, b2, bufB);
    gemm128_t<1><<<GEMM_GRID, 256, 0, stream>>>(bufB, W3, bufA);
    gcn_aggregate_pn<<<AGG_GRID, 256, 0, stream>>>(bufA, start, cnt_pad, col16, dinv, b3, bufB);
    gemm_final_pn<<<N_NODES / 8, 256, 0, stream>>>(bufB, Wl, bl, out);
}

// Round 12
// 406.977 us; speedup vs baseline: 1.7633x; 1.2148x over previous
//
#include <hip/hip_runtime.h>

#define N_NODES 50000
#define NP      50016                      // panel rows incl. sentinel row 50000
#define N_EDGES 600000
#define EDGE_CAP 750016                    // padded edge capacity (E + 3N + pad)
#define SENT    50000                      // sentinel src for pads (colw=0)
#define XS_STRIDE 132                      // LDS row stride: 128 + 4 pad
#define PANEL ((size_t)NP * 16)            // floats per 16-col feature panel

// ---------------- graph build ----------------

__global__ void count_edges(const int* __restrict__ dst, int* __restrict__ cnt) {
    int e = blockIdx.x * blockDim.x + threadIdx.x;
    if (e < N_EDGES) atomicAdd(&cnt[dst[e]], 1);
}

// start[v] = atomicAdd(total, padded_c) (uniform-address atomic -> wave-coalesced).
// Row PLACEMENT is nondeterministic across replays, but row CONTENT is
// canonicalized by sort_rows, so no float math depends on placement.
__global__ void reserve_rows(const int* __restrict__ cnt, int* __restrict__ start,
                             int* __restrict__ cnt_pad, int* __restrict__ total,
                             float* __restrict__ dinv, unsigned short* __restrict__ col16) {
    int i = blockIdx.x * blockDim.x + threadIdx.x;
    if (i < N_NODES) {
        int c = cnt[i];
        int pc = (c + 3) & ~3;
        int s = atomicAdd(total, pc);
        start[i] = s;
        cnt_pad[i] = pc;
        dinv[i] = 1.0f / sqrtf((float)(c + 1));   // +1 self-loop
        for (int p = s + c; p < s + pc; ++p) col16[p] = (unsigned short)SENT;
        if (i == 0) dinv[SENT] = 0.f;             // pads contribute exactly 0
    }
}

__global__ void csr_fill(const int* __restrict__ srcArr, const int* __restrict__ dstArr,
                         const int* __restrict__ start, int* __restrict__ fill,
                         unsigned short* __restrict__ col16) {
    int e = blockIdx.x * blockDim.x + threadIdx.x;
    if (e < N_EDGES) {
        int d = dstArr[e];
        int pos = start[d] + atomicAdd(&fill[d], 1);
        col16[pos] = (unsigned short)srcArr[e];
    }
}

// DETERMINISM: canonical per-row order (ascending src) so every call sums each
// row identically -> bitwise-stable output (bf16-boundary ulp flips killed r9).
// Then fill the sequential colw stream (incl. pads -> dinv[SENT] = 0).
__global__ void sort_rows(const int* __restrict__ start, const int* __restrict__ cnt,
                          const int* __restrict__ cnt_pad, const float* __restrict__ dinv,
                          unsigned short* __restrict__ col16, float* __restrict__ colw) {
    int v = blockIdx.x * blockDim.x + threadIdx.x;
    if (v >= N_NODES) return;
    int beg = start[v], c = cnt[v];
    for (int i = 1; i < c; ++i) {
        unsigned short key = col16[beg + i];
        int j = i - 1;
        while (j >= 0 && col16[beg + j] > key) {
            col16[beg + j + 1] = col16[beg + j];
            --j;
        }
        col16[beg + j + 1] = key;
    }
    int pc = cnt_pad[v];
    for (int p = beg; p < beg + pc; ++p) colw[p] = dinv[col16[p]];
}

// ---------------- dense GEMM [N,128]@[128,128] -> panel output ----------------
// block = 256 threads, tile = 64 rows x 128 cols, micro-tile 4x8 (r6's best:
// 46us cold / ~30us warm; 32-row variant regressed to 65us in r10).
// MODE 0: input row-major x. MODE 1: input panel layout.

template <int MODE>
__global__ __launch_bounds__(256) void gemm128_t(const float* __restrict__ X,
                                                 const float* __restrict__ W,
                                                 float* __restrict__ T) {
    __shared__ float xs[64 * XS_STRIDE];
    int tid = threadIdx.x;
    int row0 = blockIdx.x * 64;

    #pragma unroll
    for (int i = 0; i < 8; ++i) {
        int fi = tid + i * 256;
        int r  = fi >> 5;
        int c4 = (fi & 31) << 2;
        float4 v = make_float4(0.f, 0.f, 0.f, 0.f);
        int rg = row0 + r;
        if (rg < N_NODES) {
            if (MODE == 0) {
                v = *(const float4*)&X[(size_t)rg * 128 + c4];
            } else {
                int f = c4 >> 4, off = c4 & 15;
                v = *(const float4*)&X[(size_t)f * PANEL + (size_t)rg * 16 + off];
            }
        }
        float* p = &xs[r * XS_STRIDE + c4];
        p[0] = v.x; p[1] = v.y; p[2] = v.z; p[3] = v.w;
    }
    __syncthreads();

    int cg = tid & 15, rg = tid >> 4;
    int c0 = cg * 8, r0 = rg * 4;
    float acc[4][8];
    #pragma unroll
    for (int i = 0; i < 4; ++i)
        #pragma unroll
        for (int j = 0; j < 8; ++j) acc[i][j] = 0.f;

    for (int k0 = 0; k0 < 128; k0 += 4) {
        float4 a[4];
        #pragma unroll
        for (int i = 0; i < 4; ++i) a[i] = *(const float4*)&xs[(r0 + i) * XS_STRIDE + k0];
        #pragma unroll
        for (int kk = 0; kk < 4; ++kk) {
            float4 blo = *(const float4*)&W[(k0 + kk) * 128 + c0];
            float4 bhi = *(const float4*)&W[(k0 + kk) * 128 + c0 + 4];
            #pragma unroll
            for (int i = 0; i < 4; ++i) {
                float av = (kk == 0) ? a[i].x : (kk == 1) ? a[i].y : (kk == 2) ? a[i].z : a[i].w;
                acc[i][0] = fmaf(av, blo.x, acc[i][0]);
                acc[i][1] = fmaf(av, blo.y, acc[i][1]);
                acc[i][2] = fmaf(av, blo.z, acc[i][2]);
                acc[i][3] = fmaf(av, blo.w, acc[i][3]);
                acc[i][4] = fmaf(av, bhi.x, acc[i][4]);
                acc[i][5] = fmaf(av, bhi.y, acc[i][5]);
                acc[i][6] = fmaf(av, bhi.z, acc[i][6]);
                acc[i][7] = fmaf(av, bhi.w, acc[i][7]);
            }
        }
    }

    int f = c0 >> 4, off = c0 & 15;
    #pragma unroll
    for (int i = 0; i < 4; ++i) {
        int r = row0 + r0 + i;
        if (r < N_NODES) {
            float* base = &T[(size_t)f * PANEL + (size_t)r * 16 + off];
            *(float4*)&base[0] = make_float4(acc[i][0], acc[i][1], acc[i][2], acc[i][3]);
            *(float4*)&base[4] = make_float4(acc[i][4], acc[i][5], acc[i][6], acc[i][7]);
        }
    }
}

// ---------------- aggregation over panels ----------------
// blockIdx % 8 = feature panel f (-> XCD f round-robin; 3.2MB panel ~L2-resident).
// block = 256 = 64 nodes x 4 lanes (float4 per lane). Edges: u16 src (ushort4)
// + sequential f32 colw (float4), both broadcast across a node's 4 lanes.
// Rows sorted + padded to x4 with colw=0 -> branch-free deterministic loop.

__global__ __launch_bounds__(256) void gcn_aggregate_pn(
        const float* __restrict__ T, const int* __restrict__ start,
        const int* __restrict__ cnt_pad, const unsigned short* __restrict__ col16,
        const float* __restrict__ colw, const float* __restrict__ dinv,
        const float* __restrict__ bias, float* __restrict__ outp) {
    int f  = blockIdx.x & 7;
    int nb = blockIdx.x >> 3;
    int tid = threadIdx.x;
    int v = nb * 64 + (tid >> 2);
    if (v >= N_NODES) return;
    int j4 = (tid & 3) << 2;

    const float* __restrict__ Tp = T + (size_t)f * PANEL;
    float dv = dinv[v];
    const float4 tv = *(const float4*)&Tp[(size_t)v * 16 + j4];
    float4 acc = make_float4(dv * tv.x, dv * tv.y, dv * tv.z, dv * tv.w);

    int beg = start[v], end = beg + cnt_pad[v];      // multiple of 4, aligned
    for (int e = beg; e < end; e += 4) {
        ushort4 c4v = *(const ushort4*)&col16[e];
        float4  w4  = *(const float4*)&colw[e];
        int s0 = c4v.x, s1 = c4v.y, s2 = c4v.z, s3 = c4v.w;
        const float4 t0 = *(const float4*)&Tp[(size_t)s0 * 16 + j4];
        const float4 t1 = *(const float4*)&Tp[(size_t)s1 * 16 + j4];
        const float4 t2 = *(const float4*)&Tp[(size_t)s2 * 16 + j4];
        const float4 t3 = *(const float4*)&Tp[(size_t)s3 * 16 + j4];
        acc.x = fmaf(w4.x, t0.x, fmaf(w4.y, t1.x, fmaf(w4.z, t2.x, fmaf(w4.w, t3.x, acc.x))));
        acc.y = fmaf(w4.x, t0.y, fmaf(w4.y, t1.y, fmaf(w4.z, t2.y, fmaf(w4.w, t3.y, acc.y))));
        acc.z = fmaf(w4.x, t0.z, fmaf(w4.y, t1.z, fmaf(w4.z, t2.z, fmaf(w4.w, t3.z, acc.z))));
        acc.w = fmaf(w4.x, t0.w, fmaf(w4.y, t1.w, fmaf(w4.z, t2.w, fmaf(w4.w, t3.w, acc.w))));
    }

    const float4 b4 = *(const float4*)&bias[f * 16 + j4];
    float4 r;
    r.x = fmaxf(fmaf(dv, acc.x, b4.x), 0.f);
    r.y = fmaxf(fmaf(dv, acc.y, b4.y), 0.f);
    r.z = fmaxf(fmaf(dv, acc.z, b4.z), 0.f);
    r.w = fmaxf(fmaf(dv, acc.w, b4.w), 0.f);
    *(float4*)&outp[(size_t)f * PANEL + (size_t)v * 16 + j4] = r;
}

// ---------------- final linear [N,128]@[128,32] + bias, panel input ----------------

__global__ __launch_bounds__(256) void gemm_final_pn(
        const float* __restrict__ Hp, const float* __restrict__ Wl,
        const float* __restrict__ bl, float* __restrict__ out32) {
    __shared__ float sh[8 * 128];
    int tid = threadIdx.x;
    int g = tid >> 5, lane = tid & 31;
    int v = blockIdx.x * 8 + g;          // grid = 6250 exactly
    int c4 = lane << 2;
    int f = c4 >> 4, off = c4 & 15;
    const float4 hv = *(const float4*)&Hp[(size_t)f * PANEL + (size_t)v * 16 + off];
    *(float4*)&sh[g * 128 + c4] = hv;
    __syncthreads();

    float o = bl[lane];
    const float* hrow = &sh[g * 128];
    #pragma unroll 8
    for (int j = 0; j < 128; ++j)
        o = fmaf(hrow[j], Wl[j * 32 + lane], o);
    out32[(size_t)v * 32 + lane] = o;
}

// ---------------- launch ----------------

extern "C" void kernel_launch(void* const* d_in, const int* in_sizes, int n_in,
                              void* d_out, int out_size, void* d_ws, size_t ws_size,
                              hipStream_t stream) {
    const float* x      = (const float*)d_in[0];
    const int*   ei     = (const int*)d_in[1];
    const int*   srcArr = ei;
    const int*   dstArr = ei + N_EDGES;
    const float* W1 = (const float*)d_in[2];
    const float* b1 = (const float*)d_in[3];
    const float* W2 = (const float*)d_in[4];
    const float* b2 = (const float*)d_in[5];
    const float* W3 = (const float*)d_in[6];
    const float* b3 = (const float*)d_in[7];
    const float* Wl = (const float*)d_in[8];
    const float* bl = (const float*)d_in[9];
    float* out = (float*)d_out;

    // workspace layout (~56.7 MB)
    float* bufA   = (float*)d_ws;                             // 8*PANEL
    float* bufB   = bufA + 8 * PANEL;                         // 8*PANEL
    unsigned short* col16 = (unsigned short*)(bufB + 8 * PANEL); // EDGE_CAP u16
    float* colw   = (float*)(col16 + EDGE_CAP);               // EDGE_CAP f32
    float* dinv   = colw + EDGE_CAP;                          // N+1
    int*   cnt    = (int*)(dinv + N_NODES + 1);               // N   <- memset base
    int*   fill   = cnt + N_NODES;                            // N
    int*   total  = fill + N_NODES;                           // 1   <- memset end
    int*   start  = total + 1;                                // N
    int*   cnt_pad= start + N_NODES;                          // N

    hipMemsetAsync(cnt, 0, (size_t)(2 * N_NODES + 1) * sizeof(int), stream);
    count_edges <<<(N_EDGES + 255) / 256, 256, 0, stream>>>(dstArr, cnt);
    reserve_rows<<<(N_NODES + 255) / 256, 256, 0, stream>>>(cnt, start, cnt_pad, total, dinv, col16);
    csr_fill    <<<(N_EDGES + 255) / 256, 256, 0, stream>>>(srcArr, dstArr, start, fill, col16);
    sort_rows   <<<(N_NODES + 255) / 256, 256, 0, stream>>>(start, cnt, cnt_pad, dinv, col16, colw);

    const int GEMM_GRID = (N_NODES + 63) / 64;           // 782
    const int AGG_GRID  = ((N_NODES + 63) / 64) * 8;     // 6256: blockIdx%8 = panel/XCD

    gemm128_t<0><<<GEMM_GRID, 256, 0, stream>>>(x, W1, bufA);
    gcn_aggregate_pn<<<AGG_GRID, 256, 0, stream>>>(bufA, start, cnt_pad, col16, colw, dinv, b1, bufB);
    gemm128_t<1><<<GEMM_GRID, 256, 0, stream>>>(bufB, W2, bufA);
    gcn_aggregate_pn<<<AGG_GRID, 256, 0, stream>>>(bufA, start, cnt_pad, col16, colw, dinv, b2, bufB);
    gemm128_t<1><<<GEMM_GRID, 256, 0, stream>>>(bufB, W3, bufA);
    gcn_aggregate_pn<<<AGG_GRID, 256, 0, stream>>>(bufA, start, cnt_pad, col16, colw, dinv, b3, bufB);
    gemm_final_pn<<<N_NODES / 8, 256, 0, stream>>>(bufB, Wl, bl, out);
}

// Round 13
// 381.284 us; speedup vs baseline: 1.8822x; 1.0674x over previous
//
#include <hip/hip_runtime.h>

#define N_NODES 50000
#define NP      50016                      // panel rows incl. sentinel row 50000
#define N_EDGES 600000
#define EDGE_CAP 750016                    // padded edge capacity (E + 3N + pad)
#define SENT    50000                      // sentinel src for pads (colw=0)
#define XS_STRIDE 132                      // LDS row stride: 128 + 4 pad
#define PANEL ((size_t)NP * 16)            // floats per 16-col feature panel
#define SORT_CAP 48                        // LDS sort capacity (Poisson(12) max ~35)
#define SORT_STRIDE 50                     // u16 stride: 100B -> bank stride 25, conflict-free

// ---------------- graph build ----------------

__global__ void count_edges(const int* __restrict__ dst, int* __restrict__ cnt) {
    int e = blockIdx.x * blockDim.x + threadIdx.x;
    if (e < N_EDGES) atomicAdd(&cnt[dst[e]], 1);
}

// start[v] = atomicAdd(total, padded_c) (uniform-address atomic -> wave-coalesced).
// Row PLACEMENT is nondeterministic across replays, but row CONTENT is
// canonicalized by sort_rows, so no float math depends on placement.
__global__ void reserve_rows(const int* __restrict__ cnt, int* __restrict__ start,
                             int* __restrict__ cnt_pad, int* __restrict__ total,
                             float* __restrict__ dinv, unsigned short* __restrict__ col16) {
    int i = blockIdx.x * blockDim.x + threadIdx.x;
    if (i < N_NODES) {
        int c = cnt[i];
        int pc = (c + 3) & ~3;
        int s = atomicAdd(total, pc);
        start[i] = s;
        cnt_pad[i] = pc;
        dinv[i] = 1.0f / sqrtf((float)(c + 1));   // +1 self-loop
        for (int p = s + c; p < s + pc; ++p) col16[p] = (unsigned short)SENT;
        if (i == 0) dinv[SENT] = 0.f;             // pads contribute exactly 0
    }
}

__global__ void csr_fill(const int* __restrict__ srcArr, const int* __restrict__ dstArr,
                         const int* __restrict__ start, int* __restrict__ fill,
                         unsigned short* __restrict__ col16) {
    int e = blockIdx.x * blockDim.x + threadIdx.x;
    if (e < N_EDGES) {
        int d = dstArr[e];
        int pos = start[d] + atomicAdd(&fill[d], 1);
        col16[pos] = (unsigned short)srcArr[e];
    }
}

// DETERMINISM: canonical per-row order (ascending src) -> bitwise-stable sums.
// r12 lesson: global-memory insertion sort was 63us at 5% occupancy (dependent
// ~200cyc loads, 196-block grid). Sort in LDS instead: ~30cyc dependent ops,
// 782-block grid. Global-path fallback for deg>SORT_CAP (never fires: fixed
// Poisson(12) graph) keeps correctness unconditional.
__global__ __launch_bounds__(64) void sort_rows(
        const int* __restrict__ start, const int* __restrict__ cnt,
        const int* __restrict__ cnt_pad, const float* __restrict__ dinv,
        unsigned short* __restrict__ col16, float* __restrict__ colw) {
    __shared__ unsigned short buf[64 * SORT_STRIDE];
    int lane = threadIdx.x;
    int v = blockIdx.x * 64 + lane;
    if (v >= N_NODES) return;
    int beg = start[v], c = cnt[v];
    unsigned short* row = &buf[lane * SORT_STRIDE];
    if (c <= SORT_CAP) {
        for (int i = 0; i < c; ++i) row[i] = col16[beg + i];
        for (int i = 1; i < c; ++i) {
            unsigned short key = row[i];
            int j = i - 1;
            while (j >= 0 && row[j] > key) { row[j + 1] = row[j]; --j; }
            row[j + 1] = key;
        }
        for (int i = 0; i < c; ++i) col16[beg + i] = row[i];
    } else {   // unconditional-correctness fallback (not expected to fire)
        for (int i = 1; i < c; ++i) {
            unsigned short key = col16[beg + i];
            int j = i - 1;
            while (j >= 0 && col16[beg + j] > key) {
                col16[beg + j + 1] = col16[beg + j];
                --j;
            }
            col16[beg + j + 1] = key;
        }
    }
    int pc = cnt_pad[v];
    for (int p = beg; p < beg + pc; ++p) colw[p] = dinv[col16[p]];
}

// ---------------- dense GEMM [N,128]@[128,128] -> panel output ----------------
// block = 256 threads, tile = 64 rows x 128 cols, micro-tile 4x8 (r6's best:
// 46us cold / ~30us warm; 32-row variant regressed to 65us in r10).
// MODE 0: input row-major x. MODE 1: input panel layout.

template <int MODE>
__global__ __launch_bounds__(256) void gemm128_t(const float* __restrict__ X,
                                                 const float* __restrict__ W,
                                                 float* __restrict__ T) {
    __shared__ float xs[64 * XS_STRIDE];
    int tid = threadIdx.x;
    int row0 = blockIdx.x * 64;

    #pragma unroll
    for (int i = 0; i < 8; ++i) {
        int fi = tid + i * 256;
        int r  = fi >> 5;
        int c4 = (fi & 31) << 2;
        float4 v = make_float4(0.f, 0.f, 0.f, 0.f);
        int rg = row0 + r;
        if (rg < N_NODES) {
            if (MODE == 0) {
                v = *(const float4*)&X[(size_t)rg * 128 + c4];
            } else {
                int f = c4 >> 4, off = c4 & 15;
                v = *(const float4*)&X[(size_t)f * PANEL + (size_t)rg * 16 + off];
            }
        }
        float* p = &xs[r * XS_STRIDE + c4];
        p[0] = v.x; p[1] = v.y; p[2] = v.z; p[3] = v.w;
    }
    __syncthreads();

    int cg = tid & 15, rg = tid >> 4;
    int c0 = cg * 8, r0 = rg * 4;
    float acc[4][8];
    #pragma unroll
    for (int i = 0; i < 4; ++i)
        #pragma unroll
        for (int j = 0; j < 8; ++j) acc[i][j] = 0.f;

    for (int k0 = 0; k0 < 128; k0 += 4) {
        float4 a[4];
        #pragma unroll
        for (int i = 0; i < 4; ++i) a[i] = *(const float4*)&xs[(r0 + i) * XS_STRIDE + k0];
        #pragma unroll
        for (int kk = 0; kk < 4; ++kk) {
            float4 blo = *(const float4*)&W[(k0 + kk) * 128 + c0];
            float4 bhi = *(const float4*)&W[(k0 + kk) * 128 + c0 + 4];
            #pragma unroll
            for (int i = 0; i < 4; ++i) {
                float av = (kk == 0) ? a[i].x : (kk == 1) ? a[i].y : (kk == 2) ? a[i].z : a[i].w;
                acc[i][0] = fmaf(av, blo.x, acc[i][0]);
                acc[i][1] = fmaf(av, blo.y, acc[i][1]);
                acc[i][2] = fmaf(av, blo.z, acc[i][2]);
                acc[i][3] = fmaf(av, blo.w, acc[i][3]);
                acc[i][4] = fmaf(av, bhi.x, acc[i][4]);
                acc[i][5] = fmaf(av, bhi.y, acc[i][5]);
                acc[i][6] = fmaf(av, bhi.z, acc[i][6]);
                acc[i][7] = fmaf(av, bhi.w, acc[i][7]);
            }
        }
    }

    int f = c0 >> 4, off = c0 & 15;
    #pragma unroll
    for (int i = 0; i < 4; ++i) {
        int r = row0 + r0 + i;
        if (r < N_NODES) {
            float* base = &T[(size_t)f * PANEL + (size_t)r * 16 + off];
            *(float4*)&base[0] = make_float4(acc[i][0], acc[i][1], acc[i][2], acc[i][3]);
            *(float4*)&base[4] = make_float4(acc[i][4], acc[i][5], acc[i][6], acc[i][7]);
        }
    }
}

// ---------------- aggregation over panels ----------------
// blockIdx % 8 = feature panel f (-> XCD f round-robin; 3.2MB panel ~L2-resident).
// block = 256 = 64 nodes x 4 lanes (float4 per lane). Edges: u16 src (ushort4)
// + sequential f32 colw (float4), both broadcast across a node's 4 lanes.
// Rows sorted + padded to x4 with colw=0 -> branch-free deterministic loop.

__global__ __launch_bounds__(256) void gcn_aggregate_pn(
        const float* __restrict__ T, const int* __restrict__ start,
        const int* __restrict__ cnt_pad, const unsigned short* __restrict__ col16,
        const float* __restrict__ colw, const float* __restrict__ dinv,
        const float* __restrict__ bias, float* __restrict__ outp) {
    int f  = blockIdx.x & 7;
    int nb = blockIdx.x >> 3;
    int tid = threadIdx.x;
    int v = nb * 64 + (tid >> 2);
    if (v >= N_NODES) return;
    int j4 = (tid & 3) << 2;

    const float* __restrict__ Tp = T + (size_t)f * PANEL;
    float dv = dinv[v];
    const float4 tv = *(const float4*)&Tp[(size_t)v * 16 + j4];
    float4 acc = make_float4(dv * tv.x, dv * tv.y, dv * tv.z, dv * tv.w);

    int beg = start[v], end = beg + cnt_pad[v];      // multiple of 4, aligned
    for (int e = beg; e < end; e += 4) {
        ushort4 c4v = *(const ushort4*)&col16[e];
        float4  w4  = *(const float4*)&colw[e];
        int s0 = c4v.x, s1 = c4v.y, s2 = c4v.z, s3 = c4v.w;
        const float4 t0 = *(const float4*)&Tp[(size_t)s0 * 16 + j4];
        const float4 t1 = *(const float4*)&Tp[(size_t)s1 * 16 + j4];
        const float4 t2 = *(const float4*)&Tp[(size_t)s2 * 16 + j4];
        const float4 t3 = *(const float4*)&Tp[(size_t)s3 * 16 + j4];
        acc.x = fmaf(w4.x, t0.x, fmaf(w4.y, t1.x, fmaf(w4.z, t2.x, fmaf(w4.w, t3.x, acc.x))));
        acc.y = fmaf(w4.x, t0.y, fmaf(w4.y, t1.y, fmaf(w4.z, t2.y, fmaf(w4.w, t3.y, acc.y))));
        acc.z = fmaf(w4.x, t0.z, fmaf(w4.y, t1.z, fmaf(w4.z, t2.z, fmaf(w4.w, t3.z, acc.z))));
        acc.w = fmaf(w4.x, t0.w, fmaf(w4.y, t1.w, fmaf(w4.z, t2.w, fmaf(w4.w, t3.w, acc.w))));
    }

    const float4 b4 = *(const float4*)&bias[f * 16 + j4];
    float4 r;
    r.x = fmaxf(fmaf(dv, acc.x, b4.x), 0.f);
    r.y = fmaxf(fmaf(dv, acc.y, b4.y), 0.f);
    r.z = fmaxf(fmaf(dv, acc.z, b4.z), 0.f);
    r.w = fmaxf(fmaf(dv, acc.w, b4.w), 0.f);
    *(float4*)&outp[(size_t)f * PANEL + (size_t)v * 16 + j4] = r;
}

// ---------------- final linear [N,128]@[128,32] + bias, panel input ----------------

__global__ __launch_bounds__(256) void gemm_final_pn(
        const float* __restrict__ Hp, const float* __restrict__ Wl,
        const float* __restrict__ bl, float* __restrict__ out32) {
    __shared__ float sh[8 * 128];
    int tid = threadIdx.x;
    int g = tid >> 5, lane = tid & 31;
    int v = blockIdx.x * 8 + g;          // grid = 6250 exactly
    int c4 = lane << 2;
    int f = c4 >> 4, off = c4 & 15;
    const float4 hv = *(const float4*)&Hp[(size_t)f * PANEL + (size_t)v * 16 + off];
    *(float4*)&sh[g * 128 + c4] = hv;
    __syncthreads();

    float o = bl[lane];
    const float* hrow = &sh[g * 128];
    #pragma unroll 8
    for (int j = 0; j < 128; ++j)
        o = fmaf(hrow[j], Wl[j * 32 + lane], o);
    out32[(size_t)v * 32 + lane] = o;
}

// ---------------- launch ----------------

extern "C" void kernel_launch(void* const* d_in, const int* in_sizes, int n_in,
                              void* d_out, int out_size, void* d_ws, size_t ws_size,
                              hipStream_t stream) {
    const float* x      = (const float*)d_in[0];
    const int*   ei     = (const int*)d_in[1];
    const int*   srcArr = ei;
    const int*   dstArr = ei + N_EDGES;
    const float* W1 = (const float*)d_in[2];
    const float* b1 = (const float*)d_in[3];
    const float* W2 = (const float*)d_in[4];
    const float* b2 = (const float*)d_in[5];
    const float* W3 = (const float*)d_in[6];
    const float* b3 = (const float*)d_in[7];
    const float* Wl = (const float*)d_in[8];
    const float* bl = (const float*)d_in[9];
    float* out = (float*)d_out;

    // workspace layout (~56.7 MB)
    float* bufA   = (float*)d_ws;                             // 8*PANEL
    float* bufB   = bufA + 8 * PANEL;                         // 8*PANEL
    unsigned short* col16 = (unsigned short*)(bufB + 8 * PANEL); // EDGE_CAP u16
    float* colw   = (float*)(col16 + EDGE_CAP);               // EDGE_CAP f32
    float* dinv   = colw + EDGE_CAP;                          // N+1
    int*   cnt    = (int*)(dinv + N_NODES + 1);               // N   <- memset base
    int*   fill   = cnt + N_NODES;                            // N
    int*   total  = fill + N_NODES;                           // 1   <- memset end
    int*   start  = total + 1;                                // N
    int*   cnt_pad= start + N_NODES;                          // N

    hipMemsetAsync(cnt, 0, (size_t)(2 * N_NODES + 1) * sizeof(int), stream);
    count_edges <<<(N_EDGES + 255) / 256, 256, 0, stream>>>(dstArr, cnt);
    reserve_rows<<<(N_NODES + 255) / 256, 256, 0, stream>>>(cnt, start, cnt_pad, total, dinv, col16);
    csr_fill    <<<(N_EDGES + 255) / 256, 256, 0, stream>>>(srcArr, dstArr, start, fill, col16);
    sort_rows   <<<(N_NODES + 63) / 64, 64, 0, stream>>>(start, cnt, cnt_pad, dinv, col16, colw);

    const int GEMM_GRID = (N_NODES + 63) / 64;           // 782
    const int AGG_GRID  = ((N_NODES + 63) / 64) * 8;     // 6256: blockIdx%8 = panel/XCD

    gemm128_t<0><<<GEMM_GRID, 256, 0, stream>>>(x, W1, bufA);
    gcn_aggregate_pn<<<AGG_GRID, 256, 0, stream>>>(bufA, start, cnt_pad, col16, colw, dinv, b1, bufB);
    gemm128_t<1><<<GEMM_GRID, 256, 0, stream>>>(bufB, W2, bufA);
    gcn_aggregate_pn<<<AGG_GRID, 256, 0, stream>>>(bufA, start, cnt_pad, col16, colw, dinv, b2, bufB);
    gemm128_t<1><<<GEMM_GRID, 256, 0, stream>>>(bufB, W3, bufA);
    gcn_aggregate_pn<<<AGG_GRID, 256, 0, stream>>>(bufA, start, cnt_pad, col16, colw, dinv, b3, bufB);
    gemm_final_pn<<<N_NODES / 8, 256, 0, stream>>>(bufB, Wl, bl, out);
}